// Round 7
// baseline (401.099 us; speedup 1.0000x reference)
//
#include <hip/hip_runtime.h>

// ---------------------------------------------------------------------------
// Problem constants (B=2, S=2048, D=1024, H=16, DK=64, DFF=4096)
// External I/O FP32; internal GEMM operands bf16 (MFMA), fp32 accumulate.
// ---------------------------------------------------------------------------
#define BATCH 2
#define SEQ   2048
#define DMODEL 1024
#define NHEAD 16
#define DHEAD 64
#define DFF_  4096
#define MROWS (BATCH*SEQ)   // 4096
#define EPS 1e-6f

typedef unsigned short u16;
typedef unsigned int u32;
typedef __bf16 bf16x8 __attribute__((ext_vector_type(8)));
typedef float  f32x4  __attribute__((ext_vector_type(4)));
typedef u32    u32x2  __attribute__((ext_vector_type(2)));

__device__ __forceinline__ float bf2f(u16 h) {
    union { u32 u; float f; } v; v.u = ((u32)h) << 16; return v.f;
}
__device__ __forceinline__ u16 f2bf(float f) {
    union { float f; u32 u; } v; v.f = f;
    u32 u = v.u;
    u32 r = (u + 0x7fffu + ((u >> 16) & 1u)) >> 16;
    return (u16)r;
}

// async global->LDS DMA, 16 B per lane; LDS dest is wave-uniform base + lane*16
__device__ __forceinline__ void async16(const u16* g, u16* l) {
    __builtin_amdgcn_global_load_lds((const __attribute__((address_space(1))) void*)g,
                                     (__attribute__((address_space(3))) void*)l,
                                     16, 0, 0);
}

// ---------------------------------------------------------------------------
// Transpose + convert: fp32 [R,C] -> bf16 [C,R]   (R,C multiples of 32)
// ---------------------------------------------------------------------------
__global__ __launch_bounds__(256) void transpose_cvt(const float* __restrict__ in,
                                                     u16* __restrict__ out,
                                                     int R, int C) {
    __shared__ float tile[32][33];
    int c0 = blockIdx.x * 32, r0 = blockIdx.y * 32;
    int x = threadIdx.x, y = threadIdx.y;   // block (32,8)
    #pragma unroll
    for (int i = 0; i < 32; i += 8)
        tile[y + i][x] = in[(size_t)(r0 + y + i) * C + c0 + x];
    __syncthreads();
    #pragma unroll
    for (int i = 0; i < 32; i += 8)
        out[(size_t)(c0 + y + i) * R + r0 + x] = f2bf(tile[x][y + i]);
}

// ---------------------------------------------------------------------------
// Per-head V transpose WITH per-64-tile key permutation pi(c)=(c&3)*16+(c>>2):
//   vtp[b][h][d][kt + c] = V[b][kt + pi(c)][h*64 + d]
// This matches flash_attn's permuted P layout (P col' = llo*4 + j holds the
// original key j*16+llo; pi(llo*4+j) = j*16+llo). PV's key-sum is order-
// invariant as long as P and V^T use the same key order.
// grid (SEQ/64, B*H), block 256.
// ---------------------------------------------------------------------------
__global__ __launch_bounds__(256) void transpose_v_perm(const u16* __restrict__ qkv,
                                                        u16* __restrict__ vtp) {
    __shared__ u16 tile[64][72];   // [key_local][d]
    int kt = blockIdx.x * 64;
    int bh = blockIdx.y; int b = bh >> 4, h = bh & 15;
    const u16* in = qkv + ((size_t)(b * SEQ + kt)) * 3072 + 2 * DMODEL + h * DHEAD;
    u16* out = vtp + ((size_t)bh * DHEAD) * SEQ;
    int t = threadIdx.x;
    int r = t >> 3, c8 = (t & 7) * 8;
    #pragma unroll
    for (int pass = 0; pass < 2; pass++) {
        int row = r + pass * 32;
        uint4 v = *(const uint4*)(in + (size_t)row * 3072 + c8);
        *(uint4*)&tile[row][c8] = v;
    }
    __syncthreads();
    #pragma unroll
    for (int pass = 0; pass < 2; pass++) {
        int d = r + pass * 32;
        u16 o8[8];
        #pragma unroll
        for (int e = 0; e < 8; e++) {
            int c = c8 + e;
            o8[e] = tile[(c & 3) * 16 + (c >> 2)][d];
        }
        *(uint4*)(out + (size_t)d * SEQ + kt + c8) = *(const uint4*)o8;
    }
}

// ---------------------------------------------------------------------------
// LayerNorm (TF-style: biased std, eps added to std), row length 1024.
// fp32 in, bf16 out. grid = rows, block = 256 (4 elems/thread).
// ---------------------------------------------------------------------------
__global__ __launch_bounds__(256) void ln_kernel(const float* __restrict__ x,
                                                 const float* __restrict__ alpha,
                                                 const float* __restrict__ beta,
                                                 u16* __restrict__ out) {
    int row = blockIdx.x;
    int t = threadIdx.x;
    const float* xr = x + (size_t)row * DMODEL;
    float4 xv = ((const float4*)xr)[t];
    float f0 = xv.x, f1 = xv.y, f2 = xv.z, f3 = xv.w;
    float s1 = f0 + f1 + f2 + f3;
    float s2 = f0*f0 + f1*f1 + f2*f2 + f3*f3;
    #pragma unroll
    for (int off = 32; off >= 1; off >>= 1) {
        s1 += __shfl_xor(s1, off);
        s2 += __shfl_xor(s2, off);
    }
    __shared__ float r1[4], r2[4];
    int w = t >> 6, lane = t & 63;
    if (lane == 0) { r1[w] = s1; r2[w] = s2; }
    __syncthreads();
    s1 = r1[0] + r1[1] + r1[2] + r1[3];
    s2 = r2[0] + r2[1] + r2[2] + r2[3];
    float mean = s1 * (1.0f / DMODEL);
    float var  = s2 * (1.0f / DMODEL) - mean * mean;
    var = fmaxf(var, 0.0f);
    float inv = 1.0f / (sqrtf(var) + EPS);
    float4 av = ((const float4*)alpha)[t];
    float4 bv = ((const float4*)beta)[t];
    ushort4 ov;
    ov.x = f2bf(av.x * (f0 - mean) * inv + bv.x);
    ov.y = f2bf(av.y * (f1 - mean) * inv + bv.y);
    ov.z = f2bf(av.z * (f2 - mean) * inv + bv.z);
    ov.w = f2bf(av.w * (f3 - mean) * inv + bv.w);
    ((ushort4*)(out + (size_t)row * DMODEL))[t] = ov;
}

// ---------------------------------------------------------------------------
// MFMA GEMM (m97 structure, tile-templated):  C[M,N] = A[M,K] @ B[K,N],
// B given transposed (BT[N,K]), both bf16. global_load_lds width-16 staging;
// k-blocks XOR-swizzled (slot = kblk ^ (row&7)) -> frag ds_read_b128s 2-way.
// 4 waves in a 2x2 grid; each wave owns AI x AJ 16x16 output tiles.
// AI=AJ=4 -> 128x128 (32KB LDS); AI=AJ=2 -> 64x64 (16KB LDS, for narrow-N
// GEMMs that need >=4 blocks/CU to hide latency).
// ---------------------------------------------------------------------------
#define BK 64

template <int AI, int AJ, bool OUT_F32>
__global__ __launch_bounds__(256) void gemm_bt(const u16* __restrict__ A,
                                               const u16* __restrict__ BT,
                                               void* __restrict__ Cp,
                                               const float* __restrict__ bias,
                                               const float* __restrict__ residual,
                                               int M, int N, int K, int do_relu) {
    constexpr int BMt = AI * 32, BNt = AJ * 32;
    __shared__ u16 As[BMt * BK];   // row-major stride 64, swizzled k-slots
    __shared__ u16 Bs[BNt * BK];
    int t = threadIdx.x;
    int m0 = blockIdx.y * BMt, n0 = blockIdx.x * BNt;
    int lane = t & 63, w = t >> 6;
    int wr = w >> 1, wc = w & 1;
    int lhi = lane >> 4, llo = lane & 15;
    int sr = lane >> 3, sk = lane & 7;     // staging: 8 lanes per row
    int skx = (sk ^ sr) * 8;               // swizzled k-block (row&7 == sr)

    f32x4 acc[AI][AJ] = {};

    const u16* Ab = A  + (size_t)m0 * K + skx;
    const u16* Bb = BT + (size_t)n0 * K + skx;

    for (int k0 = 0; k0 < K; k0 += BK) {
        __syncthreads();
        #pragma unroll
        for (int j = 0; j < AI; j++) {
            int blk = w * AI + j;          // stages rows blk*8 .. blk*8+7
            async16(Ab + (size_t)(blk * 8 + sr) * K + k0, &As[blk * 512]);
        }
        #pragma unroll
        for (int j = 0; j < AJ; j++) {
            int blk = w * AJ + j;
            async16(Bb + (size_t)(blk * 8 + sr) * K + k0, &Bs[blk * 512]);
        }
        __syncthreads();   // drains vmcnt (global_load_lds) before frag reads
        #pragma unroll
        for (int kk = 0; kk < 2; kk++) {
            int slot = ((kk * 4 + lhi) ^ (llo & 7)) * 8;
            bf16x8 af[AI], bfr[AJ];
            #pragma unroll
            for (int i = 0; i < AI; i++)
                af[i]  = *(const bf16x8*)(&As[(wr * 16 * AI + i * 16 + llo) * 64 + slot]);
            #pragma unroll
            for (int j = 0; j < AJ; j++)
                bfr[j] = *(const bf16x8*)(&Bs[(wc * 16 * AJ + j * 16 + llo) * 64 + slot]);
            #pragma unroll
            for (int i = 0; i < AI; i++)
                #pragma unroll
                for (int j = 0; j < AJ; j++)
                    acc[i][j] = __builtin_amdgcn_mfma_f32_16x16x32_bf16(af[i], bfr[j], acc[i][j], 0, 0, 0);
        }
    }

    #pragma unroll
    for (int i = 0; i < AI; i++) {
        #pragma unroll
        for (int rr = 0; rr < 4; rr++) {
            int row = m0 + wr * 16 * AI + i * 16 + lhi * 4 + rr;
            #pragma unroll
            for (int j = 0; j < AJ; j++) {
                int col = n0 + wc * 16 * AJ + j * 16 + llo;
                float v = acc[i][j][rr];
                if (bias)      v += bias[col];
                if (residual)  v += residual[(size_t)row * N + col];
                if (do_relu)   v = fmaxf(v, 0.0f);
                size_t idx = (size_t)row * N + col;
                if (OUT_F32) ((float*)Cp)[idx] = v;
                else         ((u16*)Cp)[idx]   = f2bf(v);
            }
        }
    }
}

// ---------------------------------------------------------------------------
// Flash attention v4. Block = 128 thr (2 waves), Q-tile 64 (wave owns 32 q),
// 32 K/V tiles of 64 keys. grid (32,16,2) = 1024 blocks -> 4 blocks/CU.
// No max-subtraction softmax (see R5 justification; masked -> exp2(-1e12)=0,
// l is a plain associative per-lane sum, reduced once in the epilogue).
// Key trick: P is stored KEY-PERMUTED (col' = llo*4+j), so each lane's 4
// values are one contiguous ds_write_b64 and pf is a single ds_read_b128;
// V^T is pre-permuted identically by transpose_v_perm. kf/vf LDS reads are
// shared across both 16-row m-frags (2x amortization vs v3).
// Mask folded as additive bias (0 / -1e12) before exp2.
// LDS: 9216 (Q-stage 8192 / P 2x4608 alias) + 8192 + 8192 + 256 = 25.8 KB.
// ---------------------------------------------------------------------------
#define PSTR 72
#define SCL 0.18033688f   // log2(e)/8

__global__ __launch_bounds__(128) void flash_attn(const u16* __restrict__ qkv,
                                                  const u16* __restrict__ vtp,
                                                  const int* __restrict__ mask,
                                                  u16* __restrict__ ctx) {
    __shared__ u16 QPs[2 * 32 * PSTR];  // 9216 B: Q staging (first 8192 B), then P
    __shared__ u16 Ks[64 * 64];
    __shared__ u16 VTs[64 * 64];
    __shared__ float mbias[64];

    int t = threadIdx.x;
    int wv = t >> 6, lane = t & 63, lhi = lane >> 4, llo = lane & 15;
    int sr = lane >> 3, sk = lane & 7;
    int skx = (sk ^ sr) * 8;
    int q0 = blockIdx.x * 64, h = blockIdx.y, b = blockIdx.z;

    const u16* Qg  = qkv + ((size_t)(b * SEQ + q0)) * 3072 + h * DHEAD;
    const u16* Kg  = qkv + ((size_t)(b * SEQ)) * 3072 + DMODEL + h * DHEAD;
    const u16* VTg = vtp + ((size_t)((b * NHEAD + h) * DHEAD)) * SEQ;  // [d][key' perm]

    // ---- stage Q via DMA: 64 rows x 64 d, swizzled d-blocks ----
    #pragma unroll
    for (int j = 0; j < 4; j++) {
        int blk = wv * 4 + j;
        async16(Qg + (size_t)(blk * 8 + sr) * 3072 + skx, &QPs[blk * 512]);
    }
    __syncthreads();
    bf16x8 qf[2][2];   // [m-frag][kk]
    #pragma unroll
    for (int mi = 0; mi < 2; mi++)
        #pragma unroll
        for (int kk = 0; kk < 2; kk++)
            qf[mi][kk] = *(const bf16x8*)&QPs[(wv * 32 + mi * 16 + llo) * 64 +
                                              ((kk * 4 + lhi) ^ (llo & 7)) * 8];

    u16* Ps = QPs + wv * (32 * PSTR);   // per-wave 32 x 64 P tile (key-permuted)

    float l_part[2][4] = {};
    f32x4 o_acc[2][4] = {};

    for (int kt = 0; kt < SEQ; kt += 64) {
        __syncthreads();   // prev-iter Ks/VTs reads done (iter 0: qf reads drained)
        #pragma unroll
        for (int j = 0; j < 4; j++) {
            int blk = wv * 4 + j;
            async16(Kg  + (size_t)(kt + blk * 8 + sr) * 3072 + skx, &Ks[blk * 512]);
            async16(VTg + (size_t)(blk * 8 + sr) * SEQ + kt + skx,  &VTs[blk * 512]);
        }
        if (t < 64) mbias[t] = (mask[b * SEQ + kt + t] == 0) ? -1.0e12f : 0.0f;
        __syncthreads();

        // ---- S = Q K^T: 32 q x 64 keys per wave (kf shared across m-frags) ----
        f32x4 s0[4] = {}, s1[4] = {};
        #pragma unroll
        for (int kk = 0; kk < 2; kk++) {
            #pragma unroll
            for (int j = 0; j < 4; j++) {
                bf16x8 kf = *(const bf16x8*)&Ks[(j * 16 + llo) * 64 +
                                                ((kk * 4 + lhi) ^ (llo & 7)) * 8];
                s0[j] = __builtin_amdgcn_mfma_f32_16x16x32_bf16(qf[0][kk], kf, s0[j], 0, 0, 0);
                s1[j] = __builtin_amdgcn_mfma_f32_16x16x32_bf16(qf[1][kk], kf, s1[j], 0, 0, 0);
            }
        }
        // ---- mask bias (orig key order: col j*16+llo) ----
        float mb[4];
        #pragma unroll
        for (int j = 0; j < 4; j++) mb[j] = mbias[j * 16 + llo];

        // ---- p = 2^(s*SCL + mb); permuted b64 store; per-lane l sum ----
        #pragma unroll
        for (int mi = 0; mi < 2; mi++) {
            const f32x4* s = mi ? s1 : s0;
            #pragma unroll
            for (int rr = 0; rr < 4; rr++) {
                u32 pu[4];
                #pragma unroll
                for (int j = 0; j < 4; j++) {
                    float p = __builtin_amdgcn_exp2f(__builtin_fmaf(s[j][rr], SCL, mb[j]));
                    l_part[mi][rr] += p;
                    union { float f; u32 u; } c; c.f = p;
                    pu[j] = c.u;
                }
                u32x2 w;
                w[0] = (pu[0] >> 16) | (pu[1] & 0xffff0000u);
                w[1] = (pu[2] >> 16) | (pu[3] & 0xffff0000u);
                *(u32x2*)&Ps[(mi * 16 + lhi * 4 + rr) * PSTR + llo * 4] = w;
            }
        }
        // ---- O += P V (vf shared across m-frags; pf single b128) ----
        #pragma unroll
        for (int kk = 0; kk < 2; kk++) {
            bf16x8 pf0 = *(const bf16x8*)&Ps[(0 * 16 + llo) * PSTR + kk * 32 + lhi * 8];
            bf16x8 pf1 = *(const bf16x8*)&Ps[(1 * 16 + llo) * PSTR + kk * 32 + lhi * 8];
            #pragma unroll
            for (int nb = 0; nb < 4; nb++) {
                bf16x8 vf = *(const bf16x8*)&VTs[(nb * 16 + llo) * 64 +
                                                 ((kk * 4 + lhi) ^ (llo & 7)) * 8];
                o_acc[0][nb] = __builtin_amdgcn_mfma_f32_16x16x32_bf16(pf0, vf, o_acc[0][nb], 0, 0, 0);
                o_acc[1][nb] = __builtin_amdgcn_mfma_f32_16x16x32_bf16(pf1, vf, o_acc[1][nb], 0, 0, 0);
            }
        }
    }

    // ---- epilogue: reduce l across the 16 llo lanes, ctx = O / l ----
    #pragma unroll
    for (int mi = 0; mi < 2; mi++) {
        #pragma unroll
        for (int rr = 0; rr < 4; rr++) {
            float l = l_part[mi][rr];
            #pragma unroll
            for (int off = 1; off <= 8; off <<= 1) l += __shfl_xor(l, off);
            float inv = __builtin_amdgcn_rcpf(l);
            int row = q0 + wv * 32 + mi * 16 + lhi * 4 + rr;
            #pragma unroll
            for (int nb = 0; nb < 4; nb++) {
                int col = h * DHEAD + nb * 16 + llo;
                ctx[((size_t)(b * SEQ) + row) * DMODEL + col] = f2bf(o_acc[mi][nb][rr] * inv);
            }
        }
    }
}

// ---------------------------------------------------------------------------
// Host launcher
// ---------------------------------------------------------------------------
extern "C" void kernel_launch(void* const* d_in, const int* in_sizes, int n_in,
                              void* d_out, int out_size, void* d_ws, size_t ws_size,
                              hipStream_t stream) {
    (void)in_sizes; (void)n_in; (void)out_size; (void)ws_size;
    const float* x    = (const float*)d_in[0];
    const int* mask   = (const int*)d_in[1];
    const float* wq   = (const float*)d_in[2];
    const float* wk   = (const float*)d_in[3];
    const float* wv   = (const float*)d_in[4];
    const float* wo   = (const float*)d_in[5];
    const float* w1   = (const float*)d_in[6];
    const float* b1   = (const float*)d_in[7];
    const float* w2   = (const float*)d_in[8];
    const float* b2   = (const float*)d_in[9];
    const float* ln1a = (const float*)d_in[10];
    const float* ln1b = (const float*)d_in[11];
    const float* ln2a = (const float*)d_in[12];
    const float* ln2b = (const float*)d_in[13];
    float* out = (float*)d_out;

    // Workspace layout (byte offsets):
    // [0,6) wqkvT | [6,8) woT | [8,16) w1T | [16,24) w2T | [24,32) xn
    // [32,48) x2 fp32 (vtp aliases [32,40) during attention phase only)
    // [48,56) ctx | [56,80) qkv | [56,88) ff1 (reuse, qkv dead by FFN1)
    char* wsb = (char*)d_ws;
    const size_t MB = 1024 * 1024;
    u16*   wqkvT = (u16*)(wsb + 0);
    u16*   woT   = (u16*)(wsb + 6 * MB);
    u16*   w1T   = (u16*)(wsb + 8 * MB);
    u16*   w2T   = (u16*)(wsb + 16 * MB);
    u16*   xn    = (u16*)(wsb + 24 * MB);
    float* x2    = (float*)(wsb + 32 * MB);
    u16*   vtp   = (u16*)(wsb + 32 * MB);   // bf16 [2][16][64][2048] perm, 8 MB
    u16*   ctx   = (u16*)(wsb + 48 * MB);
    u16*   qkv   = (u16*)(wsb + 56 * MB);
    u16*   ff1   = (u16*)(wsb + 56 * MB);

    dim3 tb(32, 8);
    transpose_cvt<<<dim3(DMODEL/32, DMODEL/32), tb, 0, stream>>>(wq, wqkvT,               DMODEL, DMODEL);
    transpose_cvt<<<dim3(DMODEL/32, DMODEL/32), tb, 0, stream>>>(wk, wqkvT + 1024*1024,   DMODEL, DMODEL);
    transpose_cvt<<<dim3(DMODEL/32, DMODEL/32), tb, 0, stream>>>(wv, wqkvT + 2*1024*1024, DMODEL, DMODEL);
    transpose_cvt<<<dim3(DMODEL/32, DMODEL/32), tb, 0, stream>>>(wo, woT,                 DMODEL, DMODEL);
    transpose_cvt<<<dim3(DFF_/32,  DMODEL/32),  tb, 0, stream>>>(w1, w1T,                 DMODEL, DFF_);
    transpose_cvt<<<dim3(DMODEL/32, DFF_/32),   tb, 0, stream>>>(w2, w2T,                 DFF_, DMODEL);

    // LN1: xn = LN(x)
    ln_kernel<<<MROWS, 256, 0, stream>>>(x, ln1a, ln1b, xn);
    // QKV GEMM: [4096,1024]@[1024,3072], 128x128 tiles (768 blocks, 3/CU)
    gemm_bt<4,4,false><<<dim3(3072/128, MROWS/128), 256, 0, stream>>>(xn, wqkvT, qkv,
                                                                      nullptr, nullptr,
                                                                      MROWS, 3072, DMODEL, 0);
    // V transpose (key-permuted) for DMA + b64-P staging
    transpose_v_perm<<<dim3(SEQ/64, BATCH*NHEAD), 256, 0, stream>>>(qkv, vtp);
    // flash attention -> ctx bf16
    flash_attn<<<dim3(SEQ/64, NHEAD, BATCH), 128, 0, stream>>>(qkv, vtp, mask, ctx);
    // O-projection + residual: x2 = x + ctx @ wo, 64x64 tiles (1024 blocks, 4/CU)
    gemm_bt<2,2,true><<<dim3(DMODEL/64, MROWS/64), 256, 0, stream>>>(ctx, woT, x2,
                                                                     nullptr, x,
                                                                     MROWS, DMODEL, DMODEL, 0);
    // LN2
    ln_kernel<<<MROWS, 256, 0, stream>>>(x2, ln2a, ln2b, xn);
    // FFN1: ff1 = relu(xn @ w1 + b1), 128x128 tiles (1024 blocks, 4/CU)
    gemm_bt<4,4,false><<<dim3(DFF_/128, MROWS/128), 256, 0, stream>>>(xn, w1T, ff1,
                                                                     b1, nullptr,
                                                                     MROWS, DFF_, DMODEL, 1);
    // FFN2: out = x2 + ff1 @ w2 + b2, 64x64 tiles (1024 blocks, 4/CU)
    gemm_bt<2,2,true><<<dim3(DMODEL/64, MROWS/64), 256, 0, stream>>>(ff1, w2T, out,
                                                                    b2, x2,
                                                                    MROWS, DMODEL, DFF_, 0);
}

// Round 8
// 386.932 us; speedup vs baseline: 1.0366x; 1.0366x over previous
//
#include <hip/hip_runtime.h>

// ---------------------------------------------------------------------------
// Problem constants (B=2, S=2048, D=1024, H=16, DK=64, DFF=4096)
// External I/O FP32; internal GEMM operands bf16 (MFMA), fp32 accumulate.
// ---------------------------------------------------------------------------
#define BATCH 2
#define SEQ   2048
#define DMODEL 1024
#define NHEAD 16
#define DHEAD 64
#define DFF_  4096
#define MROWS (BATCH*SEQ)   // 4096
#define EPS 1e-6f

typedef unsigned short u16;
typedef unsigned int u32;
typedef __bf16 bf16x8 __attribute__((ext_vector_type(8)));
typedef float  f32x4  __attribute__((ext_vector_type(4)));
typedef u32    u32x2  __attribute__((ext_vector_type(2)));

__device__ __forceinline__ float bf2f(u16 h) {
    union { u32 u; float f; } v; v.u = ((u32)h) << 16; return v.f;
}
__device__ __forceinline__ u16 f2bf(float f) {
    union { float f; u32 u; } v; v.f = f;
    u32 u = v.u;
    u32 r = (u + 0x7fffu + ((u >> 16) & 1u)) >> 16;
    return (u16)r;
}

// async global->LDS DMA, 16 B per lane; LDS dest is wave-uniform base + lane*16
__device__ __forceinline__ void async16(const u16* g, u16* l) {
    __builtin_amdgcn_global_load_lds((const __attribute__((address_space(1))) void*)g,
                                     (__attribute__((address_space(3))) void*)l,
                                     16, 0, 0);
}

// ---------------------------------------------------------------------------
// Transpose + convert: fp32 [R,C] -> bf16 [C,R]   (R,C multiples of 32)
// ---------------------------------------------------------------------------
__global__ __launch_bounds__(256) void transpose_cvt(const float* __restrict__ in,
                                                     u16* __restrict__ out,
                                                     int R, int C) {
    __shared__ float tile[32][33];
    int c0 = blockIdx.x * 32, r0 = blockIdx.y * 32;
    int x = threadIdx.x, y = threadIdx.y;   // block (32,8)
    #pragma unroll
    for (int i = 0; i < 32; i += 8)
        tile[y + i][x] = in[(size_t)(r0 + y + i) * C + c0 + x];
    __syncthreads();
    #pragma unroll
    for (int i = 0; i < 32; i += 8)
        out[(size_t)(c0 + y + i) * R + r0 + x] = f2bf(tile[x][y + i]);
}

// ---------------------------------------------------------------------------
// Per-head V transpose WITH per-64-tile key permutation pi(c)=(c&3)*16+(c>>2):
//   vtp[b][h][d][kt + c] = V[b][kt + pi(c)][h*64 + d]
// Matches flash_attn's permuted P layout (P col' = llo*4 + j holds original
// key j*16+llo; pi(llo*4+j) = j*16+llo). PV's key-sum is order-invariant as
// long as P and V^T use the same key order.  grid (SEQ/64, B*H), block 256.
// ---------------------------------------------------------------------------
__global__ __launch_bounds__(256) void transpose_v_perm(const u16* __restrict__ qkv,
                                                        u16* __restrict__ vtp) {
    __shared__ u16 tile[64][72];   // [key_local][d]
    int kt = blockIdx.x * 64;
    int bh = blockIdx.y; int b = bh >> 4, h = bh & 15;
    const u16* in = qkv + ((size_t)(b * SEQ + kt)) * 3072 + 2 * DMODEL + h * DHEAD;
    u16* out = vtp + ((size_t)bh * DHEAD) * SEQ;
    int t = threadIdx.x;
    int r = t >> 3, c8 = (t & 7) * 8;
    #pragma unroll
    for (int pass = 0; pass < 2; pass++) {
        int row = r + pass * 32;
        uint4 v = *(const uint4*)(in + (size_t)row * 3072 + c8);
        *(uint4*)&tile[row][c8] = v;
    }
    __syncthreads();
    #pragma unroll
    for (int pass = 0; pass < 2; pass++) {
        int d = r + pass * 32;
        u16 o8[8];
        #pragma unroll
        for (int e = 0; e < 8; e++) {
            int c = c8 + e;
            o8[e] = tile[(c & 3) * 16 + (c >> 2)][d];
        }
        *(uint4*)(out + (size_t)d * SEQ + kt + c8) = *(const uint4*)o8;
    }
}

// ---------------------------------------------------------------------------
// LayerNorm (TF-style: biased std, eps added to std), row length 1024.
// fp32 in, bf16 out. grid = rows, block = 256 (4 elems/thread).
// ---------------------------------------------------------------------------
__global__ __launch_bounds__(256) void ln_kernel(const float* __restrict__ x,
                                                 const float* __restrict__ alpha,
                                                 const float* __restrict__ beta,
                                                 u16* __restrict__ out) {
    int row = blockIdx.x;
    int t = threadIdx.x;
    const float* xr = x + (size_t)row * DMODEL;
    float4 xv = ((const float4*)xr)[t];
    float f0 = xv.x, f1 = xv.y, f2 = xv.z, f3 = xv.w;
    float s1 = f0 + f1 + f2 + f3;
    float s2 = f0*f0 + f1*f1 + f2*f2 + f3*f3;
    #pragma unroll
    for (int off = 32; off >= 1; off >>= 1) {
        s1 += __shfl_xor(s1, off);
        s2 += __shfl_xor(s2, off);
    }
    __shared__ float r1[4], r2[4];
    int w = t >> 6, lane = t & 63;
    if (lane == 0) { r1[w] = s1; r2[w] = s2; }
    __syncthreads();
    s1 = r1[0] + r1[1] + r1[2] + r1[3];
    s2 = r2[0] + r2[1] + r2[2] + r2[3];
    float mean = s1 * (1.0f / DMODEL);
    float var  = s2 * (1.0f / DMODEL) - mean * mean;
    var = fmaxf(var, 0.0f);
    float inv = 1.0f / (sqrtf(var) + EPS);
    float4 av = ((const float4*)alpha)[t];
    float4 bv = ((const float4*)beta)[t];
    ushort4 ov;
    ov.x = f2bf(av.x * (f0 - mean) * inv + bv.x);
    ov.y = f2bf(av.y * (f1 - mean) * inv + bv.y);
    ov.z = f2bf(av.z * (f2 - mean) * inv + bv.z);
    ov.w = f2bf(av.w * (f3 - mean) * inv + bv.w);
    ((ushort4*)(out + (size_t)row * DMODEL))[t] = ov;
}

// ---------------------------------------------------------------------------
// MFMA GEMM (m97 structure, tile-templated):  C[M,N] = A[M,K] @ B[K,N],
// B given transposed (BT[N,K]), both bf16. global_load_lds width-16 staging;
// k-blocks XOR-swizzled (slot = kblk ^ (row&7)) -> frag ds_read_b128s
// phase-optimal (measured 0 conflicts). 4 waves, 2x2 grid; wave owns AIxAJ
// 16x16 tiles. AI=AJ=4 -> 128x128 (32KB LDS); AI=AJ=2 -> 64x64 (16KB, for
// narrow-N GEMMs needing >=4 blocks/CU).
// ---------------------------------------------------------------------------
#define BK 64

template <int AI, int AJ, bool OUT_F32>
__global__ __launch_bounds__(256) void gemm_bt(const u16* __restrict__ A,
                                               const u16* __restrict__ BT,
                                               void* __restrict__ Cp,
                                               const float* __restrict__ bias,
                                               const float* __restrict__ residual,
                                               int M, int N, int K, int do_relu) {
    constexpr int BMt = AI * 32, BNt = AJ * 32;
    __shared__ u16 As[BMt * BK];   // row-major stride 64, swizzled k-slots
    __shared__ u16 Bs[BNt * BK];
    int t = threadIdx.x;
    int m0 = blockIdx.y * BMt, n0 = blockIdx.x * BNt;
    int lane = t & 63, w = t >> 6;
    int wr = w >> 1, wc = w & 1;
    int lhi = lane >> 4, llo = lane & 15;
    int sr = lane >> 3, sk = lane & 7;     // staging: 8 lanes per row
    int skx = (sk ^ sr) * 8;               // swizzled k-block (row&7 == sr)

    f32x4 acc[AI][AJ] = {};

    const u16* Ab = A  + (size_t)m0 * K + skx;
    const u16* Bb = BT + (size_t)n0 * K + skx;

    for (int k0 = 0; k0 < K; k0 += BK) {
        __syncthreads();
        #pragma unroll
        for (int j = 0; j < AI; j++) {
            int blk = w * AI + j;          // stages rows blk*8 .. blk*8+7
            async16(Ab + (size_t)(blk * 8 + sr) * K + k0, &As[blk * 512]);
        }
        #pragma unroll
        for (int j = 0; j < AJ; j++) {
            int blk = w * AJ + j;
            async16(Bb + (size_t)(blk * 8 + sr) * K + k0, &Bs[blk * 512]);
        }
        __syncthreads();   // drains vmcnt (global_load_lds) before frag reads
        #pragma unroll
        for (int kk = 0; kk < 2; kk++) {
            int slot = ((kk * 4 + lhi) ^ (llo & 7)) * 8;
            bf16x8 af[AI], bfr[AJ];
            #pragma unroll
            for (int i = 0; i < AI; i++)
                af[i]  = *(const bf16x8*)(&As[(wr * 16 * AI + i * 16 + llo) * 64 + slot]);
            #pragma unroll
            for (int j = 0; j < AJ; j++)
                bfr[j] = *(const bf16x8*)(&Bs[(wc * 16 * AJ + j * 16 + llo) * 64 + slot]);
            #pragma unroll
            for (int i = 0; i < AI; i++)
                #pragma unroll
                for (int j = 0; j < AJ; j++)
                    acc[i][j] = __builtin_amdgcn_mfma_f32_16x16x32_bf16(af[i], bfr[j], acc[i][j], 0, 0, 0);
        }
    }

    #pragma unroll
    for (int i = 0; i < AI; i++) {
        #pragma unroll
        for (int rr = 0; rr < 4; rr++) {
            int row = m0 + wr * 16 * AI + i * 16 + lhi * 4 + rr;
            #pragma unroll
            for (int j = 0; j < AJ; j++) {
                int col = n0 + wc * 16 * AJ + j * 16 + llo;
                float v = acc[i][j][rr];
                if (bias)      v += bias[col];
                if (residual)  v += residual[(size_t)row * N + col];
                if (do_relu)   v = fmaxf(v, 0.0f);
                size_t idx = (size_t)row * N + col;
                if (OUT_F32) ((float*)Cp)[idx] = v;
                else         ((u16*)Cp)[idx]   = f2bf(v);
            }
        }
    }
}

// ---------------------------------------------------------------------------
// Flash attention v5. Block 256 thr (4 waves), Q-tile 64 (wave owns 16 q),
// 32 K/V tiles of 64 keys. grid (32,16,2)=1024 blocks -> 4/CU, 16 waves/CU.
// No max-subtraction softmax (R5 justification; masked -> exp2(-1e12) = 0;
// l = plain associative per-lane sum, one cross-lane reduce in epilogue).
// P stored KEY-PERMUTED (col' = llo*4+j) at STRIDE 64 with the same XOR
// swizzle as the gemm fragments (slot = colblk ^ (row&7)) -> store is one
// ds_write_b64, pf one ds_read_b128, zero conflicts (gemm-verified pattern).
// V^T pre-permuted identically by transpose_v_perm. Mask = additive bias.
// LDS: 8192 (Q-stage, aliased by 4x 16x64 P tiles) + 8192 + 8192 + 256.
// ---------------------------------------------------------------------------
#define SCL 0.18033688f   // log2(e)/8

__global__ __launch_bounds__(256) void flash_attn(const u16* __restrict__ qkv,
                                                  const u16* __restrict__ vtp,
                                                  const int* __restrict__ mask,
                                                  u16* __restrict__ ctx) {
    __shared__ u16 QPs[64 * 64];   // 8KB: Q staging, then per-wave P (w*1024)
    __shared__ u16 Ks[64 * 64];
    __shared__ u16 VTs[64 * 64];
    __shared__ float mbias[64];

    int t = threadIdx.x;
    int w = t >> 6, lane = t & 63, lhi = lane >> 4, llo = lane & 15;
    int sr = lane >> 3, sk = lane & 7;
    int skx = (sk ^ sr) * 8;
    int q0 = blockIdx.x * 64, h = blockIdx.y, b = blockIdx.z;

    const u16* Qg  = qkv + ((size_t)(b * SEQ + q0)) * 3072 + h * DHEAD;
    const u16* Kg  = qkv + ((size_t)(b * SEQ)) * 3072 + DMODEL + h * DHEAD;
    const u16* VTg = vtp + ((size_t)((b * NHEAD + h) * DHEAD)) * SEQ;  // [d][key']

    // ---- stage Q via DMA: 64 rows x 64 d (2 rounds), swizzled d-blocks ----
    #pragma unroll
    for (int j = 0; j < 2; j++) {
        int blk = w * 2 + j;
        async16(Qg + (size_t)(blk * 8 + sr) * 3072 + skx, &QPs[blk * 512]);
    }
    __syncthreads();
    bf16x8 qf[2];
    #pragma unroll
    for (int kk = 0; kk < 2; kk++)
        qf[kk] = *(const bf16x8*)&QPs[(w * 16 + llo) * 64 + ((kk * 4 + lhi) ^ (llo & 7)) * 8];

    u16* Ps = QPs + w * 1024;   // per-wave 16 x 64 P tile, stride 64, swizzled

    float l_part[4] = {};
    f32x4 o_acc[4] = {};

    for (int kt = 0; kt < SEQ; kt += 64) {
        __syncthreads();   // prev-iter Ks/VTs reads done; guards Q->Ps alias
        #pragma unroll
        for (int j = 0; j < 2; j++) {
            int blk = w * 2 + j;
            async16(Kg  + (size_t)(kt + blk * 8 + sr) * 3072 + skx, &Ks[blk * 512]);
            async16(VTg + (size_t)(blk * 8 + sr) * SEQ + kt + skx,  &VTs[blk * 512]);
        }
        if (t < 64) mbias[t] = (mask[b * SEQ + kt + t] == 0) ? -1.0e12f : 0.0f;
        __syncthreads();

        // ---- S = Q K^T: 16 q x 64 keys per wave ----
        f32x4 s[4] = {};
        #pragma unroll
        for (int kk = 0; kk < 2; kk++) {
            #pragma unroll
            for (int j = 0; j < 4; j++) {
                bf16x8 kf = *(const bf16x8*)&Ks[(j * 16 + llo) * 64 +
                                                ((kk * 4 + lhi) ^ (llo & 7)) * 8];
                s[j] = __builtin_amdgcn_mfma_f32_16x16x32_bf16(qf[kk], kf, s[j], 0, 0, 0);
            }
        }
        // ---- mask bias (orig key order: col j*16+llo) ----
        float mb[4];
        #pragma unroll
        for (int j = 0; j < 4; j++) mb[j] = mbias[j * 16 + llo];

        // ---- p = 2^(s*SCL + mb); permuted+swizzled b64 store; l sum ----
        #pragma unroll
        for (int rr = 0; rr < 4; rr++) {
            u32 pu[4];
            #pragma unroll
            for (int j = 0; j < 4; j++) {
                float p = __builtin_amdgcn_exp2f(__builtin_fmaf(s[j][rr], SCL, mb[j]));
                l_part[rr] += p;
                union { float f; u32 u; } c; c.f = p;
                pu[j] = c.u;
            }
            u32x2 pw;
            pw[0] = (pu[0] >> 16) | (pu[1] & 0xffff0000u);
            pw[1] = (pu[2] >> 16) | (pu[3] & 0xffff0000u);
            int prow = lhi * 4 + rr;
            *(u32x2*)&Ps[prow * 64 + ((llo >> 1) ^ (prow & 7)) * 8 + (llo & 1) * 4] = pw;
        }
        // ---- O += P V (pf single b128; same swizzle family as kf/vf) ----
        #pragma unroll
        for (int kk = 0; kk < 2; kk++) {
            bf16x8 pf = *(const bf16x8*)&Ps[llo * 64 + ((kk * 4 + lhi) ^ (llo & 7)) * 8];
            #pragma unroll
            for (int nb = 0; nb < 4; nb++) {
                bf16x8 vf = *(const bf16x8*)&VTs[(nb * 16 + llo) * 64 +
                                                 ((kk * 4 + lhi) ^ (llo & 7)) * 8];
                o_acc[nb] = __builtin_amdgcn_mfma_f32_16x16x32_bf16(pf, vf, o_acc[nb], 0, 0, 0);
            }
        }
    }

    // ---- epilogue: reduce l across the 16 llo lanes, ctx = O / l ----
    #pragma unroll
    for (int rr = 0; rr < 4; rr++) {
        float l = l_part[rr];
        #pragma unroll
        for (int off = 1; off <= 8; off <<= 1) l += __shfl_xor(l, off);
        float inv = __builtin_amdgcn_rcpf(l);
        int row = q0 + w * 16 + lhi * 4 + rr;
        #pragma unroll
        for (int nb = 0; nb < 4; nb++) {
            int col = h * DHEAD + nb * 16 + llo;
            ctx[((size_t)(b * SEQ) + row) * DMODEL + col] = f2bf(o_acc[nb][rr] * inv);
        }
    }
}

// ---------------------------------------------------------------------------
// Host launcher
// ---------------------------------------------------------------------------
extern "C" void kernel_launch(void* const* d_in, const int* in_sizes, int n_in,
                              void* d_out, int out_size, void* d_ws, size_t ws_size,
                              hipStream_t stream) {
    (void)in_sizes; (void)n_in; (void)out_size; (void)ws_size;
    const float* x    = (const float*)d_in[0];
    const int* mask   = (const int*)d_in[1];
    const float* wq   = (const float*)d_in[2];
    const float* wk   = (const float*)d_in[3];
    const float* wv   = (const float*)d_in[4];
    const float* wo   = (const float*)d_in[5];
    const float* w1   = (const float*)d_in[6];
    const float* b1   = (const float*)d_in[7];
    const float* w2   = (const float*)d_in[8];
    const float* b2   = (const float*)d_in[9];
    const float* ln1a = (const float*)d_in[10];
    const float* ln1b = (const float*)d_in[11];
    const float* ln2a = (const float*)d_in[12];
    const float* ln2b = (const float*)d_in[13];
    float* out = (float*)d_out;

    // Workspace layout (byte offsets):
    // [0,6) wqkvT | [6,8) woT | [8,16) w1T | [16,24) w2T | [24,32) xn
    // [32,48) x2 fp32 (vtp aliases [32,40) during attention phase only)
    // [48,56) ctx | [56,80) qkv | [56,88) ff1 (reuse, qkv dead by FFN1)
    char* wsb = (char*)d_ws;
    const size_t MB = 1024 * 1024;
    u16*   wqkvT = (u16*)(wsb + 0);
    u16*   woT   = (u16*)(wsb + 6 * MB);
    u16*   w1T   = (u16*)(wsb + 8 * MB);
    u16*   w2T   = (u16*)(wsb + 16 * MB);
    u16*   xn    = (u16*)(wsb + 24 * MB);
    float* x2    = (float*)(wsb + 32 * MB);
    u16*   vtp   = (u16*)(wsb + 32 * MB);   // bf16 [2][16][64][2048] perm, 8 MB
    u16*   ctx   = (u16*)(wsb + 48 * MB);
    u16*   qkv   = (u16*)(wsb + 56 * MB);
    u16*   ff1   = (u16*)(wsb + 56 * MB);

    dim3 tb(32, 8);
    transpose_cvt<<<dim3(DMODEL/32, DMODEL/32), tb, 0, stream>>>(wq, wqkvT,               DMODEL, DMODEL);
    transpose_cvt<<<dim3(DMODEL/32, DMODEL/32), tb, 0, stream>>>(wk, wqkvT + 1024*1024,   DMODEL, DMODEL);
    transpose_cvt<<<dim3(DMODEL/32, DMODEL/32), tb, 0, stream>>>(wv, wqkvT + 2*1024*1024, DMODEL, DMODEL);
    transpose_cvt<<<dim3(DMODEL/32, DMODEL/32), tb, 0, stream>>>(wo, woT,                 DMODEL, DMODEL);
    transpose_cvt<<<dim3(DFF_/32,  DMODEL/32),  tb, 0, stream>>>(w1, w1T,                 DMODEL, DFF_);
    transpose_cvt<<<dim3(DMODEL/32, DFF_/32),   tb, 0, stream>>>(w2, w2T,                 DFF_, DMODEL);

    // LN1: xn = LN(x)
    ln_kernel<<<MROWS, 256, 0, stream>>>(x, ln1a, ln1b, xn);
    // QKV GEMM: [4096,1024]@[1024,3072], 128x128 tiles (768 blocks, 3/CU)
    gemm_bt<4,4,false><<<dim3(3072/128, MROWS/128), 256, 0, stream>>>(xn, wqkvT, qkv,
                                                                      nullptr, nullptr,
                                                                      MROWS, 3072, DMODEL, 0);
    // V transpose (key-permuted) for DMA + b64-P staging
    transpose_v_perm<<<dim3(SEQ/64, BATCH*NHEAD), 256, 0, stream>>>(qkv, vtp);
    // flash attention -> ctx bf16
    flash_attn<<<dim3(SEQ/64, NHEAD, BATCH), 256, 0, stream>>>(qkv, vtp, mask, ctx);
    // O-projection + residual: x2 = x + ctx @ wo, 64x64 tiles (1024 blocks, 4/CU)
    gemm_bt<2,2,true><<<dim3(DMODEL/64, MROWS/64), 256, 0, stream>>>(ctx, woT, x2,
                                                                     nullptr, x,
                                                                     MROWS, DMODEL, DMODEL, 0);
    // LN2
    ln_kernel<<<MROWS, 256, 0, stream>>>(x2, ln2a, ln2b, xn);
    // FFN1: ff1 = relu(xn @ w1 + b1), 128x128 tiles (1024 blocks, 4/CU)
    gemm_bt<4,4,false><<<dim3(DFF_/128, MROWS/128), 256, 0, stream>>>(xn, w1T, ff1,
                                                                     b1, nullptr,
                                                                     MROWS, DFF_, DMODEL, 1);
    // FFN2: out = x2 + ff1 @ w2 + b2, 64x64 tiles (1024 blocks, 4/CU)
    gemm_bt<2,2,true><<<dim3(DMODEL/64, MROWS/64), 256, 0, stream>>>(ff1, w2T, out,
                                                                    b2, x2,
                                                                    MROWS, DMODEL, DFF_, 0);
}

// Round 9
// 366.462 us; speedup vs baseline: 1.0945x; 1.0559x over previous
//
#include <hip/hip_runtime.h>

// ---------------------------------------------------------------------------
// Problem constants (B=2, S=2048, D=1024, H=16, DK=64, DFF=4096)
// External I/O FP32; internal GEMM operands bf16 (MFMA), fp32 accumulate.
// ---------------------------------------------------------------------------
#define BATCH 2
#define SEQ   2048
#define DMODEL 1024
#define NHEAD 16
#define DHEAD 64
#define DFF_  4096
#define MROWS (BATCH*SEQ)   // 4096
#define EPS 1e-6f

typedef unsigned short u16;
typedef unsigned int u32;
typedef __bf16 bf16x8 __attribute__((ext_vector_type(8)));
typedef float  f32x4  __attribute__((ext_vector_type(4)));
typedef u32    u32x2  __attribute__((ext_vector_type(2)));

__device__ __forceinline__ float bf2f(u16 h) {
    union { u32 u; float f; } v; v.u = ((u32)h) << 16; return v.f;
}
__device__ __forceinline__ u16 f2bf(float f) {
    union { float f; u32 u; } v; v.f = f;
    u32 u = v.u;
    u32 r = (u + 0x7fffu + ((u >> 16) & 1u)) >> 16;
    return (u16)r;
}

// async global->LDS DMA, 16 B per lane; LDS dest is wave-uniform base + lane*16
__device__ __forceinline__ void async16(const u16* g, u16* l) {
    __builtin_amdgcn_global_load_lds((const __attribute__((address_space(1))) void*)g,
                                     (__attribute__((address_space(3))) void*)l,
                                     16, 0, 0);
}

// ---------------------------------------------------------------------------
// Transpose + convert: fp32 [R,C] -> bf16 [C,R]   (R,C multiples of 32)
// ---------------------------------------------------------------------------
__global__ __launch_bounds__(256) void transpose_cvt(const float* __restrict__ in,
                                                     u16* __restrict__ out,
                                                     int R, int C) {
    __shared__ float tile[32][33];
    int c0 = blockIdx.x * 32, r0 = blockIdx.y * 32;
    int x = threadIdx.x, y = threadIdx.y;   // block (32,8)
    #pragma unroll
    for (int i = 0; i < 32; i += 8)
        tile[y + i][x] = in[(size_t)(r0 + y + i) * C + c0 + x];
    __syncthreads();
    #pragma unroll
    for (int i = 0; i < 32; i += 8)
        out[(size_t)(c0 + y + i) * R + r0 + x] = f2bf(tile[x][y + i]);
}

// Fused 4x square (1024x1024) transpose+convert: z selects the matrix.
__global__ __launch_bounds__(256) void transpose_cvt4(const float* __restrict__ i0,
                                                      const float* __restrict__ i1,
                                                      const float* __restrict__ i2,
                                                      const float* __restrict__ i3,
                                                      u16* __restrict__ o0,
                                                      u16* __restrict__ o1,
                                                      u16* __restrict__ o2,
                                                      u16* __restrict__ o3) {
    __shared__ float tile[32][33];
    const float* in; u16* out;
    switch (blockIdx.z) {
        case 0: in = i0; out = o0; break;
        case 1: in = i1; out = o1; break;
        case 2: in = i2; out = o2; break;
        default: in = i3; out = o3; break;
    }
    int c0 = blockIdx.x * 32, r0 = blockIdx.y * 32;
    int x = threadIdx.x, y = threadIdx.y;
    #pragma unroll
    for (int i = 0; i < 32; i += 8)
        tile[y + i][x] = in[(size_t)(r0 + y + i) * DMODEL + c0 + x];
    __syncthreads();
    #pragma unroll
    for (int i = 0; i < 32; i += 8)
        out[(size_t)(c0 + y + i) * DMODEL + r0 + x] = f2bf(tile[x][y + i]);
}

// ---------------------------------------------------------------------------
// Per-head V transpose WITH per-64-tile key permutation pi(c)=(c&3)*16+(c>>2):
//   vtp[b][h][d][kt + c] = V[b][kt + pi(c)][h*64 + d]
// Matches flash_attn's permuted P layout. grid (SEQ/64, B*H), block 256.
// ---------------------------------------------------------------------------
__global__ __launch_bounds__(256) void transpose_v_perm(const u16* __restrict__ qkv,
                                                        u16* __restrict__ vtp) {
    __shared__ u16 tile[64][72];   // [key_local][d]
    int kt = blockIdx.x * 64;
    int bh = blockIdx.y; int b = bh >> 4, h = bh & 15;
    const u16* in = qkv + ((size_t)(b * SEQ + kt)) * 3072 + 2 * DMODEL + h * DHEAD;
    u16* out = vtp + ((size_t)bh * DHEAD) * SEQ;
    int t = threadIdx.x;
    int r = t >> 3, c8 = (t & 7) * 8;
    #pragma unroll
    for (int pass = 0; pass < 2; pass++) {
        int row = r + pass * 32;
        uint4 v = *(const uint4*)(in + (size_t)row * 3072 + c8);
        *(uint4*)&tile[row][c8] = v;
    }
    __syncthreads();
    #pragma unroll
    for (int pass = 0; pass < 2; pass++) {
        int d = r + pass * 32;
        u16 o8[8];
        #pragma unroll
        for (int e = 0; e < 8; e++) {
            int c = c8 + e;
            o8[e] = tile[(c & 3) * 16 + (c >> 2)][d];
        }
        *(uint4*)(out + (size_t)d * SEQ + kt + c8) = *(const uint4*)o8;
    }
}

// ---------------------------------------------------------------------------
// LayerNorm (TF-style: biased std, eps added to std), row length 1024.
// fp32 in, bf16 out. grid = rows, block = 256 (4 elems/thread).
// ---------------------------------------------------------------------------
__global__ __launch_bounds__(256) void ln_kernel(const float* __restrict__ x,
                                                 const float* __restrict__ alpha,
                                                 const float* __restrict__ beta,
                                                 u16* __restrict__ out) {
    int row = blockIdx.x;
    int t = threadIdx.x;
    const float* xr = x + (size_t)row * DMODEL;
    float4 xv = ((const float4*)xr)[t];
    float f0 = xv.x, f1 = xv.y, f2 = xv.z, f3 = xv.w;
    float s1 = f0 + f1 + f2 + f3;
    float s2 = f0*f0 + f1*f1 + f2*f2 + f3*f3;
    #pragma unroll
    for (int off = 32; off >= 1; off >>= 1) {
        s1 += __shfl_xor(s1, off);
        s2 += __shfl_xor(s2, off);
    }
    __shared__ float r1[4], r2[4];
    int w = t >> 6, lane = t & 63;
    if (lane == 0) { r1[w] = s1; r2[w] = s2; }
    __syncthreads();
    s1 = r1[0] + r1[1] + r1[2] + r1[3];
    s2 = r2[0] + r2[1] + r2[2] + r2[3];
    float mean = s1 * (1.0f / DMODEL);
    float var  = s2 * (1.0f / DMODEL) - mean * mean;
    var = fmaxf(var, 0.0f);
    float inv = 1.0f / (sqrtf(var) + EPS);
    float4 av = ((const float4*)alpha)[t];
    float4 bv = ((const float4*)beta)[t];
    ushort4 ov;
    ov.x = f2bf(av.x * (f0 - mean) * inv + bv.x);
    ov.y = f2bf(av.y * (f1 - mean) * inv + bv.y);
    ov.z = f2bf(av.z * (f2 - mean) * inv + bv.z);
    ov.w = f2bf(av.w * (f3 - mean) * inv + bv.w);
    ((ushort4*)(out + (size_t)row * DMODEL))[t] = ov;
}

// ---------------------------------------------------------------------------
// MFMA GEMM (m97 structure, tile-templated):  C[M,N] = A[M,K] @ B[K,N],
// B given transposed (BT[N,K]), both bf16. global_load_lds width-16 staging;
// k-blocks XOR-swizzled (slot = kblk ^ (row&7)) -> frag ds_read_b128s
// conflict-free (measured 0). 4 waves, 2x2 grid; wave owns AIxAJ 16x16 tiles.
// (4,4)=128x128/32KB; (4,2)=128x64/24KB (6 blk/CU — for short-K GEMMs that
// need block-parallelism to hide barrier drains); (2,2)=64x64/16KB.
// ---------------------------------------------------------------------------
#define BK 64

template <int AI, int AJ, bool OUT_F32>
__global__ __launch_bounds__(256) void gemm_bt(const u16* __restrict__ A,
                                               const u16* __restrict__ BT,
                                               void* __restrict__ Cp,
                                               const float* __restrict__ bias,
                                               const float* __restrict__ residual,
                                               int M, int N, int K, int do_relu) {
    constexpr int BMt = AI * 32, BNt = AJ * 32;
    __shared__ u16 As[BMt * BK];   // row-major stride 64, swizzled k-slots
    __shared__ u16 Bs[BNt * BK];
    int t = threadIdx.x;
    int m0 = blockIdx.y * BMt, n0 = blockIdx.x * BNt;
    int lane = t & 63, w = t >> 6;
    int wr = w >> 1, wc = w & 1;
    int lhi = lane >> 4, llo = lane & 15;
    int sr = lane >> 3, sk = lane & 7;     // staging: 8 lanes per row
    int skx = (sk ^ sr) * 8;               // swizzled k-block (row&7 == sr)

    f32x4 acc[AI][AJ] = {};

    const u16* Ab = A  + (size_t)m0 * K + skx;
    const u16* Bb = BT + (size_t)n0 * K + skx;

    for (int k0 = 0; k0 < K; k0 += BK) {
        __syncthreads();
        #pragma unroll
        for (int j = 0; j < AI; j++) {
            int blk = w * AI + j;          // stages rows blk*8 .. blk*8+7
            async16(Ab + (size_t)(blk * 8 + sr) * K + k0, &As[blk * 512]);
        }
        #pragma unroll
        for (int j = 0; j < AJ; j++) {
            int blk = w * AJ + j;
            async16(Bb + (size_t)(blk * 8 + sr) * K + k0, &Bs[blk * 512]);
        }
        __syncthreads();   // drains vmcnt (global_load_lds) before frag reads
        #pragma unroll
        for (int kk = 0; kk < 2; kk++) {
            int slot = ((kk * 4 + lhi) ^ (llo & 7)) * 8;
            bf16x8 af[AI], bfr[AJ];
            #pragma unroll
            for (int i = 0; i < AI; i++)
                af[i]  = *(const bf16x8*)(&As[(wr * 16 * AI + i * 16 + llo) * 64 + slot]);
            #pragma unroll
            for (int j = 0; j < AJ; j++)
                bfr[j] = *(const bf16x8*)(&Bs[(wc * 16 * AJ + j * 16 + llo) * 64 + slot]);
            #pragma unroll
            for (int i = 0; i < AI; i++)
                #pragma unroll
                for (int j = 0; j < AJ; j++)
                    acc[i][j] = __builtin_amdgcn_mfma_f32_16x16x32_bf16(af[i], bfr[j], acc[i][j], 0, 0, 0);
        }
    }

    #pragma unroll
    for (int i = 0; i < AI; i++) {
        #pragma unroll
        for (int rr = 0; rr < 4; rr++) {
            int row = m0 + wr * 16 * AI + i * 16 + lhi * 4 + rr;
            #pragma unroll
            for (int j = 0; j < AJ; j++) {
                int col = n0 + wc * 16 * AJ + j * 16 + llo;
                float v = acc[i][j][rr];
                if (bias)      v += bias[col];
                if (residual)  v += residual[(size_t)row * N + col];
                if (do_relu)   v = fmaxf(v, 0.0f);
                size_t idx = (size_t)row * N + col;
                if (OUT_F32) ((float*)Cp)[idx] = v;
                else         ((u16*)Cp)[idx]   = f2bf(v);
            }
        }
    }
}

// ---------------------------------------------------------------------------
// Flash attention v5. Block 256 thr (4 waves), Q-tile 64 (wave owns 16 q),
// 32 K/V tiles of 64 keys. grid (32,16,2)=1024 blocks -> 4/CU.
// No max-subtraction softmax (masked -> exp2(-1e12)=0; l = associative
// per-lane sum, one cross-lane reduce in epilogue). P stored KEY-PERMUTED
// (col' = llo*4+j) at stride 64 with the gemm XOR swizzle -> one ds_write_b64
// store, one ds_read_b128 pf, zero conflicts. V^T pre-permuted identically.
// LDS: 8192 (Q-stage aliased by per-wave P) + 8192 + 8192 + 256.
// ---------------------------------------------------------------------------
#define SCL 0.18033688f   // log2(e)/8

__global__ __launch_bounds__(256) void flash_attn(const u16* __restrict__ qkv,
                                                  const u16* __restrict__ vtp,
                                                  const int* __restrict__ mask,
                                                  u16* __restrict__ ctx) {
    __shared__ u16 QPs[64 * 64];   // 8KB: Q staging, then per-wave P (w*1024)
    __shared__ u16 Ks[64 * 64];
    __shared__ u16 VTs[64 * 64];
    __shared__ float mbias[64];

    int t = threadIdx.x;
    int w = t >> 6, lane = t & 63, lhi = lane >> 4, llo = lane & 15;
    int sr = lane >> 3, sk = lane & 7;
    int skx = (sk ^ sr) * 8;
    int q0 = blockIdx.x * 64, h = blockIdx.y, b = blockIdx.z;

    const u16* Qg  = qkv + ((size_t)(b * SEQ + q0)) * 3072 + h * DHEAD;
    const u16* Kg  = qkv + ((size_t)(b * SEQ)) * 3072 + DMODEL + h * DHEAD;
    const u16* VTg = vtp + ((size_t)((b * NHEAD + h) * DHEAD)) * SEQ;  // [d][key']

    // ---- stage Q via DMA: 64 rows x 64 d (2 rounds), swizzled d-blocks ----
    #pragma unroll
    for (int j = 0; j < 2; j++) {
        int blk = w * 2 + j;
        async16(Qg + (size_t)(blk * 8 + sr) * 3072 + skx, &QPs[blk * 512]);
    }
    __syncthreads();
    bf16x8 qf[2];
    #pragma unroll
    for (int kk = 0; kk < 2; kk++)
        qf[kk] = *(const bf16x8*)&QPs[(w * 16 + llo) * 64 + ((kk * 4 + lhi) ^ (llo & 7)) * 8];

    u16* Ps = QPs + w * 1024;   // per-wave 16 x 64 P tile, stride 64, swizzled

    float l_part[4] = {};
    f32x4 o_acc[4] = {};

    for (int kt = 0; kt < SEQ; kt += 64) {
        __syncthreads();   // prev-iter Ks/VTs reads done; guards Q->Ps alias
        #pragma unroll
        for (int j = 0; j < 2; j++) {
            int blk = w * 2 + j;
            async16(Kg  + (size_t)(kt + blk * 8 + sr) * 3072 + skx, &Ks[blk * 512]);
            async16(VTg + (size_t)(blk * 8 + sr) * SEQ + kt + skx,  &VTs[blk * 512]);
        }
        if (t < 64) mbias[t] = (mask[b * SEQ + kt + t] == 0) ? -1.0e12f : 0.0f;
        __syncthreads();

        // ---- S = Q K^T: 16 q x 64 keys per wave ----
        f32x4 s[4] = {};
        #pragma unroll
        for (int kk = 0; kk < 2; kk++) {
            #pragma unroll
            for (int j = 0; j < 4; j++) {
                bf16x8 kf = *(const bf16x8*)&Ks[(j * 16 + llo) * 64 +
                                                ((kk * 4 + lhi) ^ (llo & 7)) * 8];
                s[j] = __builtin_amdgcn_mfma_f32_16x16x32_bf16(qf[kk], kf, s[j], 0, 0, 0);
            }
        }
        // ---- mask bias (orig key order: col j*16+llo) ----
        float mb[4];
        #pragma unroll
        for (int j = 0; j < 4; j++) mb[j] = mbias[j * 16 + llo];

        // ---- p = 2^(s*SCL + mb); permuted+swizzled b64 store; l sum ----
        #pragma unroll
        for (int rr = 0; rr < 4; rr++) {
            u32 pu[4];
            #pragma unroll
            for (int j = 0; j < 4; j++) {
                float p = __builtin_amdgcn_exp2f(__builtin_fmaf(s[j][rr], SCL, mb[j]));
                l_part[rr] += p;
                union { float f; u32 u; } c; c.f = p;
                pu[j] = c.u;
            }
            u32x2 pw;
            pw[0] = (pu[0] >> 16) | (pu[1] & 0xffff0000u);
            pw[1] = (pu[2] >> 16) | (pu[3] & 0xffff0000u);
            int prow = lhi * 4 + rr;
            *(u32x2*)&Ps[prow * 64 + ((llo >> 1) ^ (prow & 7)) * 8 + (llo & 1) * 4] = pw;
        }
        // ---- O += P V (pf single b128; same swizzle family as kf/vf) ----
        #pragma unroll
        for (int kk = 0; kk < 2; kk++) {
            bf16x8 pf = *(const bf16x8*)&Ps[llo * 64 + ((kk * 4 + lhi) ^ (llo & 7)) * 8];
            #pragma unroll
            for (int nb = 0; nb < 4; nb++) {
                bf16x8 vf = *(const bf16x8*)&VTs[(nb * 16 + llo) * 64 +
                                                 ((kk * 4 + lhi) ^ (llo & 7)) * 8];
                o_acc[nb] = __builtin_amdgcn_mfma_f32_16x16x32_bf16(pf, vf, o_acc[nb], 0, 0, 0);
            }
        }
    }

    // ---- epilogue: reduce l across the 16 llo lanes, ctx = O / l ----
    #pragma unroll
    for (int rr = 0; rr < 4; rr++) {
        float l = l_part[rr];
        #pragma unroll
        for (int off = 1; off <= 8; off <<= 1) l += __shfl_xor(l, off);
        float inv = __builtin_amdgcn_rcpf(l);
        int row = q0 + w * 16 + lhi * 4 + rr;
        #pragma unroll
        for (int nb = 0; nb < 4; nb++) {
            int col = h * DHEAD + nb * 16 + llo;
            ctx[((size_t)(b * SEQ) + row) * DMODEL + col] = f2bf(o_acc[nb][rr] * inv);
        }
    }
}

// ---------------------------------------------------------------------------
// Host launcher
// ---------------------------------------------------------------------------
extern "C" void kernel_launch(void* const* d_in, const int* in_sizes, int n_in,
                              void* d_out, int out_size, void* d_ws, size_t ws_size,
                              hipStream_t stream) {
    (void)in_sizes; (void)n_in; (void)out_size; (void)ws_size;
    const float* x    = (const float*)d_in[0];
    const int* mask   = (const int*)d_in[1];
    const float* wq   = (const float*)d_in[2];
    const float* wk   = (const float*)d_in[3];
    const float* wv   = (const float*)d_in[4];
    const float* wo   = (const float*)d_in[5];
    const float* w1   = (const float*)d_in[6];
    const float* b1   = (const float*)d_in[7];
    const float* w2   = (const float*)d_in[8];
    const float* b2   = (const float*)d_in[9];
    const float* ln1a = (const float*)d_in[10];
    const float* ln1b = (const float*)d_in[11];
    const float* ln2a = (const float*)d_in[12];
    const float* ln2b = (const float*)d_in[13];
    float* out = (float*)d_out;

    // Workspace layout (byte offsets):
    // [0,6) wqkvT | [6,8) woT | [8,16) w1T | [16,24) w2T | [24,32) xn
    // [32,48) x2 fp32 (vtp aliases [32,40) during attention phase only)
    // [48,56) ctx | [56,80) qkv | [56,88) ff1 (reuse, qkv dead by FFN1)
    char* wsb = (char*)d_ws;
    const size_t MB = 1024 * 1024;
    u16*   wqkvT = (u16*)(wsb + 0);
    u16*   woT   = (u16*)(wsb + 6 * MB);
    u16*   w1T   = (u16*)(wsb + 8 * MB);
    u16*   w2T   = (u16*)(wsb + 16 * MB);
    u16*   xn    = (u16*)(wsb + 24 * MB);
    float* x2    = (float*)(wsb + 32 * MB);
    u16*   vtp   = (u16*)(wsb + 32 * MB);   // bf16 [2][16][64][2048] perm, 8 MB
    u16*   ctx   = (u16*)(wsb + 48 * MB);
    u16*   qkv   = (u16*)(wsb + 56 * MB);
    u16*   ff1   = (u16*)(wsb + 56 * MB);

    dim3 tb(32, 8);
    // fused 4x 1024^2 weight transposes (wq, wk, wv, wo)
    transpose_cvt4<<<dim3(DMODEL/32, DMODEL/32, 4), tb, 0, stream>>>(
        wq, wk, wv, wo,
        wqkvT, wqkvT + 1024*1024, wqkvT + 2*1024*1024, woT);
    transpose_cvt<<<dim3(DFF_/32,  DMODEL/32),  tb, 0, stream>>>(w1, w1T, DMODEL, DFF_);
    transpose_cvt<<<dim3(DMODEL/32, DFF_/32),   tb, 0, stream>>>(w2, w2T, DFF_, DMODEL);

    // LN1: xn = LN(x)
    ln_kernel<<<MROWS, 256, 0, stream>>>(x, ln1a, ln1b, xn);
    // QKV GEMM: [4096,1024]@[1024,3072], 128x64 tiles (1536 blocks, 6/CU)
    gemm_bt<4,2,false><<<dim3(3072/64, MROWS/128), 256, 0, stream>>>(xn, wqkvT, qkv,
                                                                     nullptr, nullptr,
                                                                     MROWS, 3072, DMODEL, 0);
    // V transpose (key-permuted) for DMA + b64-P staging
    transpose_v_perm<<<dim3(SEQ/64, BATCH*NHEAD), 256, 0, stream>>>(qkv, vtp);
    // flash attention -> ctx bf16
    flash_attn<<<dim3(SEQ/64, NHEAD, BATCH), 256, 0, stream>>>(qkv, vtp, mask, ctx);
    // O-projection + residual: x2 = x + ctx @ wo, 64x64 tiles (1024 blocks)
    gemm_bt<2,2,true><<<dim3(DMODEL/64, MROWS/64), 256, 0, stream>>>(ctx, woT, x2,
                                                                     nullptr, x,
                                                                     MROWS, DMODEL, DMODEL, 0);
    // LN2
    ln_kernel<<<MROWS, 256, 0, stream>>>(x2, ln2a, ln2b, xn);
    // FFN1: ff1 = relu(xn @ w1 + b1), 128x64 tiles (2048 blocks, 6/CU by LDS)
    gemm_bt<4,2,false><<<dim3(DFF_/64, MROWS/128), 256, 0, stream>>>(xn, w1T, ff1,
                                                                    b1, nullptr,
                                                                    MROWS, DFF_, DMODEL, 1);
    // FFN2: out = x2 + ff1 @ w2 + b2, 64x64 tiles (1024 blocks)
    gemm_bt<2,2,true><<<dim3(DMODEL/64, MROWS/64), 256, 0, stream>>>(ff1, w2T, out,
                                                                    b2, x2,
                                                                    MROWS, DMODEL, DFF_, 0);
}